// Round 8
// baseline (389.244 us; speedup 1.0000x reference)
//
#include <hip/hip_runtime.h>
#include <hip/hip_bf16.h>

#define BATCH 4096
#define NTHR 512

typedef __attribute__((ext_vector_type(8))) short bf16x8;
typedef __attribute__((ext_vector_type(4))) float f32x4;
typedef __attribute__((ext_vector_type(4))) short short4v;

// CK-style barrier: drain LDS only, leave global prefetches in flight
#define BAR() asm volatile("s_waitcnt lgkmcnt(0)\n\ts_barrier" ::: "memory")
#define MFMA16(a, b, c) __builtin_amdgcn_mfma_f32_16x16x32_bf16(a, b, c, 0, 0, 0)

// expand OP over the 9 owned tiles (named registers, never an array)
#define TT_EACH(OP) OP(0) OP(1) OP(2) OP(3) OP(4) OP(5) OP(6) OP(7) OP(8)

// dh-sorted packing: group g (= degree) has cnt(g) units, prefix off1(g)
__host__ __device__ __forceinline__ int off1(int g) { return (g <= 16) ? 17 * g : 16 * g + 16; }
__host__ __device__ __forceinline__ int cntg(int g) { return (g < 16) ? 17 : 16; }
__host__ __device__ __forceinline__ int unitOf(int p) {
    int gp, jp;
    if (p < 272) { gp = p / 17; jp = p - gp * 17; }
    else         { gp = (p >> 4) - 1; jp = p & 15; }
    return gp + 63 * jp;
}
__device__ __forceinline__ short f2bf(float f) {
    __hip_bfloat16 h = __float2bfloat16(f);
    return *reinterpret_cast<short*>(&h);
}
__device__ __forceinline__ float bfrnd(float f) {
    __hip_bfloat16 h = __float2bfloat16(f);
    return __bfloat162float(h);
}

// ---------------- prep7: parallel packing (305 blocks), verified in round 7 ----------------
__global__ void prep7(const float* __restrict__ W0, const float* __restrict__ b0,
                      const float* __restrict__ W1, const float* __restrict__ b1,
                      const float* __restrict__ W2,
                      short* __restrict__ W1f, short* __restrict__ W2f,
                      short* __restrict__ W0f, float* __restrict__ b1p) {
    __shared__ short ws[16][1028];   // padded rows: 16-way -> ~4-way bank conflicts
    const int b = blockIdx.x, t = threadIdx.x;
    if (b < 288) {
        const bool isW1 = (b < 256);
        const int tile = isW1 ? (b >> 2) : ((b - 256) >> 2);
        const int chunk = isW1 ? (b & 3) : ((b - 256) & 3);
        const int n = t >> 5;
        int u;
        if (isW1) u = unitOf(tile * 16 + n);
        else      u = (n & 1) ? (64 + tile * 8 + (n >> 1)) : (tile * 8 + (n >> 1));
        const float* src = isW1 ? (W1 + (long)u * 1024) : (W2 + (long)u * 1024);
        const int c0 = (t & 31) * 4;
#pragma unroll
        for (int j = 0; j < 8; ++j) {
            int c = c0 + j * 128;
            float4 v = *(const float4*)&src[c];
            short4v sv;
            sv[0] = f2bf(v.x); sv[1] = f2bf(v.y); sv[2] = f2bf(v.z); sv[3] = f2bf(v.w);
            *(short4v*)&ws[n][c] = sv;
        }
        __syncthreads();
        const int ng = (chunk < 3) ? 16 : 15;
#pragma unroll 1
        for (int it = 0; it < 2; ++it) {
            int v = t + it * 512;
            if (v < ng * 64) {
                int gl = chunk * 16 + (v >> 6), lane2 = v & 63;
                int nn = lane2 & 15, aq2 = lane2 >> 4;
                bf16x8 pk;
#pragma unroll
                for (int e = 0; e < 8; ++e) {
                    int k = aq2 * 8 + e;
                    pk[e] = (k < cntg(gl)) ? ws[nn][gl + 63 * k] : (short)0;
                }
                if (isW1) *(bf16x8*)&W1f[(((long)gl * 64 + tile) * 64 + lane2) * 8] = pk;
                else      *(bf16x8*)&W2f[(((long)gl * 8 + tile) * 64 + lane2) * 8] = pk;
            }
        }
    } else if (b < 304) {
        const int bb = b - 288;
#pragma unroll 1
        for (int j = 0; j < 16; ++j) {
            int q = t + j * 512;
            if (q < 8064) {
                int idx = bb * 8064 + q;
                int g = idx >> 11, rem = idx & 2047;
                int n2 = rem >> 10, kt = (rem >> 9) & 1, lane2 = (rem >> 3) & 63, e = rem & 7;
                int sl = n2 * 16 + (lane2 & 15);
                int kp = kt * 32 + ((lane2 >> 4) << 3) + e;
                float val = 0.f;
                if (sl < cntg(g)) {
                    int u = unitOf(off1(g) + sl);
                    if (kp == 0) val = b0[u];
                    else if (kp - 1 <= g) val = W0[u * 64 + kp - 1];
                }
                W0f[idx] = f2bf(val);
            }
        }
    } else {
        for (int p = t; p < 1024; p += 512) b1p[p] = b1[unitOf(p)];
    }
}

// ================= made10: made7d with ZERO call boundaries (macro-inlined) =================
// Theory: made7d's 91MB scratch @ VGPR==128 under 3 allocator knobs was NOT pressure —
// the step/catchup LAMBDAS were not inlined (8 call sites x ~120 lines), so every
// by-reference capture was address-taken -> demoted to scratch pre-regalloc. made6's
// body lambda (2 sites) inlined -> zero scratch: the control. Fix: macros. Math is
// token-identical to made7d (passed, absmax 0.015625 == made6).

// -- helper macros (file scope; reference names in the expansion scope) --
#define M10_LQ(tt)    if (tt < NT) q##tt = *(const bf16x8*)&W1f[((gl_ * 64 + TLO + tt) * 64 + lane) * 8];
#define M10_APALL(tt) if (tt < NT) a##tt = MFMA16(af_, q##tt, a##tt);
#define M10_AP(tt)    if (tt < NT && tt >= t0g_) a##tt = MFMA16(af_, q##tt, a##tt);
#define M10_F0(tt) if (tt == tf0_ && j0_ >= 0 && j0_ < cg_) { \
    h2w[p2_][s2_][aq * 4 + 0][j0_] = f2bf(a##tt[0] > 0.f ? a##tt[0] : 0.f); \
    h2w[p2_][s2_][aq * 4 + 1][j0_] = f2bf(a##tt[1] > 0.f ? a##tt[1] : 0.f); \
    h2w[p2_][s2_][aq * 4 + 2][j0_] = f2bf(a##tt[2] > 0.f ? a##tt[2] : 0.f); \
    h2w[p2_][s2_][aq * 4 + 3][j0_] = f2bf(a##tt[3] > 0.f ? a##tt[3] : 0.f); }
#define M10_F1(tt) if (tfl_ != tf0_ && tt == tfl_ && j1_ < cg_) { \
    h2w[p2_][s2_][aq * 4 + 0][j1_] = f2bf(a##tt[0] > 0.f ? a##tt[0] : 0.f); \
    h2w[p2_][s2_][aq * 4 + 1][j1_] = f2bf(a##tt[1] > 0.f ? a##tt[1] : 0.f); \
    h2w[p2_][s2_][aq * 4 + 2][j1_] = f2bf(a##tt[2] > 0.f ? a##tt[2] : 0.f); \
    h2w[p2_][s2_][aq * 4 + 3][j1_] = f2bf(a##tt[3] > 0.f ? a##tt[3] : 0.f); }

#define CATCHUP(w) do { \
    _Pragma("unroll") \
    for (int gk = 0; gk < 8; ++gk) { \
        const int g_ = 8 * (w) - 9 + gk; \
        if (g_ >= 0) { \
            bf16x8 a3_ = *(const bf16x8*)&h2w[(g_ >> 3) & 1][g_ & 7][n][aq * 8]; \
            bf16x8 wb_ = *(const bf16x8*)&W2f[(((long)g_ * 8 + wv) * 64 + lane) * 8]; \
            zacc = MFMA16(a3_, wb_, zacc); \
        } \
    } \
    const int pH_ = ((w) - 1) & 1; \
    _Pragma("unroll 1") \
    for (int gk = 0; gk < 8; ++gk) { \
        bf16x8 af_ = *(const bf16x8*)&h1w[pH_][gk][n][aq * 8]; \
        const long gl_ = 8 * ((w) - 1) + gk; \
        TT_EACH(M10_LQ) \
        TT_EACH(M10_APALL) \
    } \
} while (0)

#define STEP(wq, kk, w0dU, w0d16U, w0dP, w0d16P) do { \
    const int i_ = 8 * (wq) + (kk), g_ = i_ - 1; \
    if ((kk) > 0) { \
        const int t0g_ = (off1(g_) >> 4) - TLO; \
        bf16x8 af_ = *(const bf16x8*)&h1w[(g_ >> 3) & 1][g_ & 7][n][aq * 8]; \
        TT_EACH(M10_AP) \
    } \
    if ((kk) < 7) { \
        const long gl_ = i_; \
        TT_EACH(M10_LQ) \
        const int i2_ = i_ + 1; \
        w0dP = (i2_ < 63) ? bfrnd(W0[unitOf(off1(i2_) + n) * 64 + i2_]) : 0.f; \
        w0d16P = (i2_ < 16) ? bfrnd(W0[unitOf(off1(i2_) + 16) * 64 + i2_]) : 0.f; \
    } \
    if (g_ >= 0) { \
        const int og_ = off1(g_), cg_ = cntg(g_); \
        const int tf0_ = (og_ >> 4) - TLO, tfl_ = ((og_ + cg_ - 1) >> 4) - TLO; \
        const int p2_ = (g_ >> 3) & 1, s2_ = g_ & 7; \
        const int j0_ = (tf0_ + TLO) * 16 + n - og_; \
        const int j1_ = (tfl_ + TLO) * 16 + n - og_; \
        TT_EACH(M10_F0) \
        TT_EACH(M10_F1) \
        if (cg_ == 16 && n == 0) { \
            h2w[p2_][s2_][aq * 4 + 0][16] = 0; \
            h2w[p2_][s2_][aq * 4 + 1][16] = 0; \
            h2w[p2_][s2_][aq * 4 + 2][16] = 0; \
            h2w[p2_][s2_][aq * 4 + 3][16] = 0; \
        } \
    } \
    f32x4 d0p_ = {0.f, 0.f, 0.f, 0.f}, d1p_ = {0.f, 0.f, 0.f, 0.f}; \
    const bool doH1_ = (i_ < 63); \
    if (doH1_) { \
        bf16x8 ax0_ = *(const bf16x8*)&xhist[n][aq * 8]; \
        d0p_ = MFMA16(ax0_, w0fa, d0p_); \
        if (i_ >= 32) { \
            bf16x8 ax1_ = *(const bf16x8*)&xhist[n][32 + aq * 8]; \
            d0p_ = MFMA16(ax1_, w0fb, d0p_); \
        } \
        if (i_ < 16) d1p_ = MFMA16(ax0_, w0fc, d1p_); \
    } \
    if (g_ >= 0) { \
        bf16x8 af3_ = *(const bf16x8*)&h2w[(g_ >> 3) & 1][g_ & 7][n][aq * 8]; \
        zacc = MFMA16(af3_, w2S, zacc); \
    } \
    if ((kk) < 7) { \
        const long gp_ = (i_ < 63) ? i_ : 62; \
        w2S = *(const bf16x8*)&W2f[((gp_ * 8 + wv) * 64 + lane) * 8]; \
    } \
    const int n0_ = 2 * (kk); \
    f32x4 sgv_; \
    sgv_[0] = __shfl_xor(zacc[0], 1); \
    sgv_[1] = __shfl_xor(zacc[1], 1); \
    sgv_[2] = __shfl_xor(zacc[2], 1); \
    sgv_[3] = __shfl_xor(zacc[3], 1); \
    f32x4 xv_; \
    if (n == n0_) { \
        _Pragma("unroll") \
        for (int r = 0; r < 4; ++r) { \
            const float sg_ = sgv_[r], mu_ = zacc[r]; \
            const float x_ = ureg[r] * __expf(sg_) + mu_; \
            ldjacc[r] += sg_; \
            xv_[r] = x_; \
            xLs[aq * 4 + r][i_] = x_; \
            if (doH1_) xhist[aq * 4 + r][i_ + 1] = f2bf(x_); \
        } \
    } \
    if (doH1_) { \
        const int pi_ = (i_ >> 3) & 1, si_ = i_ & 7; \
        _Pragma("unroll") \
        for (int r = 0; r < 4; ++r) { \
            float xb_ = bfrnd(__shfl(xv_[r], (lane & 48) | n0_)); \
            float h_ = d0p_[r] + xb_ * (w0dU); \
            h1w[pi_][si_][aq * 4 + r][n] = f2bf(h_ > 0.f ? h_ : 0.f); \
            if (n == 0) { \
                float h16_ = (i_ < 16) ? (d1p_[r] + xb_ * (w0d16U)) : 0.f; \
                h1w[pi_][si_][aq * 4 + r][16] = f2bf(h16_ > 0.f ? h16_ : 0.f); \
            } \
        } \
        if ((kk) < 7) { \
            const long gb_ = (i_ + 1 < 63) ? i_ + 1 : 62; \
            w0fa = *(const bf16x8*)&W0f[((gb_ * 4 + 0) * 64 + lane) * 8]; \
            w0fb = *(const bf16x8*)&W0f[((gb_ * 4 + 1) * 64 + lane) * 8]; \
            w0fc = *(const bf16x8*)&W0f[((gb_ * 4 + 2) * 64 + lane) * 8]; \
        } \
    } \
} while (0)

__global__ __attribute__((amdgpu_flat_work_group_size(NTHR, NTHR)))
__attribute__((amdgpu_waves_per_eu(2, 2))) void made10(
    const float* __restrict__ uin, const float* __restrict__ b2,
    const float* __restrict__ W0,
    const short* __restrict__ W1f, const short* __restrict__ W2f,
    const short* __restrict__ W0f, const float* __restrict__ b1p,
    float* __restrict__ out) {

    __shared__ __align__(16) short h1w[2][8][16][40];   // [par][slot][m][j], cols 17..31 stay 0
    __shared__ __align__(16) short h2w[2][8][16][40];
    __shared__ __align__(16) short xhist[16][80];       // [m][k']: k'=0 bias 1.0, k'=i+1 -> x_i
    __shared__ __align__(16) float uT[64][16];
    __shared__ __align__(16) float xLs[16][68];
    __shared__ float ldjpart[8][16];

    const int t = threadIdx.x, lane = t & 63, wv = t >> 6;
    const int n = lane & 15, aq = lane >> 4;
    const int rowbase = blockIdx.x * 16;

    {   // zero LDS (K pads must stay 0 forever)
        int* z1 = (int*)&h1w[0][0][0][0];
#pragma unroll 1
        for (int idx = t; idx < 5120; idx += NTHR) z1[idx] = 0;
        int* z2 = (int*)&h2w[0][0][0][0];
#pragma unroll 1
        for (int idx = t; idx < 5120; idx += NTHR) z2[idx] = 0;
        int* z3 = (int*)&xhist[0][0];
#pragma unroll 1
        for (int idx = t; idx < 640; idx += NTHR) z3[idx] = 0;
    }
    if (t < 256) {
        int r = t >> 4, c0 = (t & 15) * 4;
        float4 v = *(const float4*)&uin[(long)(rowbase + r) * 64 + c0];
        uT[c0 + 0][r] = v.x; uT[c0 + 1][r] = v.y; uT[c0 + 2][r] = v.z; uT[c0 + 3][r] = v.w;
    }

    // private tile range: tiles covering groups [gA, gB]
    const int gA = (wv == 0) ? 0 : 8 * wv - 1;
    const int gB = (8 * wv + 6 > 62) ? 62 : 8 * wv + 6;
    const int TLO = off1(gA) >> 4;
    const int NT = ((off1(gB) + cntg(gB) - 1) >> 4) - TLO + 1;   // 8 or 9

    // named accumulator tiles + W1 fragment registers
#define DECL_A(tt) f32x4 a##tt;
    TT_EACH(DECL_A)
#undef DECL_A
#define INIT_A(tt) { float bb_ = (tt < NT) ? b1p[(TLO + tt) * 16 + n] : 0.f; a##tt = (f32x4){bb_, bb_, bb_, bb_}; }
    TT_EACH(INIT_A)
#undef INIT_A
#define DECL_Q(tt) bf16x8 q##tt;
    TT_EACH(DECL_Q)
#undef DECL_Q

    f32x4 zacc;
    {
        int pc = wv * 16 + n;               // packed z col; orig r = (pc>>1)+64*(pc&1)
        float bz = b2[(pc >> 1) + 64 * (pc & 1)];
        zacc = (f32x4){bz, bz, bz, bz};
    }

    f32x4 ldjacc = {0.f, 0.f, 0.f, 0.f};
    bf16x8 w2S, w0fa, w0fb, w0fc;
    float w0dA = 0.f, w0d16A = 0.f, w0dB = 0.f, w0d16B = 0.f;

    BAR();
    if (t < 16) xhist[t][0] = (short)0x3F80;   // bias col = 1.0 (wave 0, same-wave first use)
    f32x4 ureg;
#pragma unroll
    for (int r = 0; r < 4; ++r) ureg[r] = uT[8 * wv + (n >> 1)][aq * 4 + r];

    // ---- 8 windows, ONE barrier each ----
#pragma unroll 1
    for (int w = 0; w < 8; ++w) {
        if (wv == w) {
            __builtin_amdgcn_s_setprio(1);
            if (w > 0) CATCHUP(w);
            const int i0 = 8 * w;
            {
                const long gz = (w > 0) ? (i0 - 1) : 0;
                w2S = *(const bf16x8*)&W2f[((gz * 8 + wv) * 64 + lane) * 8];
            }
            w0fa = *(const bf16x8*)&W0f[(((long)i0 * 4 + 0) * 64 + lane) * 8];
            w0fb = *(const bf16x8*)&W0f[(((long)i0 * 4 + 1) * 64 + lane) * 8];
            w0fc = *(const bf16x8*)&W0f[(((long)i0 * 4 + 2) * 64 + lane) * 8];
            w0dA = bfrnd(W0[unitOf(off1(i0) + n) * 64 + i0]);                        // i0<=56<63
            w0d16A = (i0 < 16) ? bfrnd(W0[unitOf(off1(i0) + 16) * 64 + i0]) : 0.f;
            STEP(w, 0, w0dA, w0d16A, w0dB, w0d16B);
            STEP(w, 1, w0dB, w0d16B, w0dA, w0d16A);
            STEP(w, 2, w0dA, w0d16A, w0dB, w0d16B);
            STEP(w, 3, w0dB, w0d16B, w0dA, w0d16A);
            STEP(w, 4, w0dA, w0d16A, w0dB, w0d16B);
            STEP(w, 5, w0dB, w0d16B, w0dA, w0d16A);
            STEP(w, 6, w0dA, w0d16A, w0dB, w0d16B);
            STEP(w, 7, w0dB, w0d16B, w0dA, w0d16A);
#pragma unroll
            for (int r = 0; r < 4; ++r) {   // ldj partial for this wave's 8 steps
                float v = ldjacc[r];
                v += __shfl_xor(v, 2);
                v += __shfl_xor(v, 4);
                v += __shfl_xor(v, 8);
                if (n == 0) ldjpart[wv][aq * 4 + r] = v;
            }
            __builtin_amdgcn_s_setprio(0);
        } else if (w > 0 && wv > w) {
            CATCHUP(w);
        }
        BAR();
    }

    if (t < 256) {
        int r = t >> 4, c = (t & 15) * 4;
        float4 v;
        v.x = xLs[r][c]; v.y = xLs[r][c + 1]; v.z = xLs[r][c + 2]; v.w = xLs[r][c + 3];
        *(float4*)&out[(long)(rowbase + r) * 64 + c] = v;
    }
    if (t < 16) {
        float s = 0.f;
#pragma unroll
        for (int w2 = 0; w2 < 8; ++w2) s += ldjpart[w2][t];
        out[(long)BATCH * 64 + rowbase + t] = s;
    }
}

extern "C" void kernel_launch(void* const* d_in, const int* in_sizes, int n_in,
                              void* d_out, int out_size, void* d_ws, size_t ws_size,
                              hipStream_t stream) {
    (void)in_sizes; (void)n_in; (void)out_size; (void)ws_size;
    const float* u  = (const float*)d_in[0];
    const float* W0 = (const float*)d_in[1];
    const float* b0 = (const float*)d_in[2];
    const float* W1 = (const float*)d_in[3];
    const float* b1 = (const float*)d_in[4];
    const float* W2 = (const float*)d_in[5];
    const float* b2 = (const float*)d_in[6];
    float* out = (float*)d_out;

    // d_ws layout (bytes): W1f 4,128,768 | W2f 516,096 | W0f 258,048 | b1p 4,096
    short* W1f = (short*)d_ws;
    short* W2f = (short*)((char*)d_ws + 4128768);
    short* W0f = (short*)((char*)d_ws + 4128768 + 516096);
    float* b1p = (float*)((char*)d_ws + 4128768 + 516096 + 258048);

    prep7<<<dim3(305), dim3(512), 0, stream>>>(W0, b0, W1, b1, W2, W1f, W2f, W0f, b1p);
    made10<<<dim3(BATCH / 16), dim3(NTHR), 0, stream>>>(u, b2, W0, W1f, W2f, W0f, b1p, out);
}